// Round 12
// baseline (934.083 us; speedup 1.0000x reference)
//
#include <hip/hip_runtime.h>

// FusedLoRAQKV on MI355X (gfx950).
// Y_p = X @ (W_p + 2 * B_p @ A_p)^T  for p in {Q,K,V}
//
// Pipeline:
//   1. cvt_x:    X fp32 -> bf16
//   2. merge_w3: W' = bf16(W + 2*B@A), all three projections, one launch
//   3. gemm32:   256x256 tile, BK=64, 8 waves, mfma_f32_32x32x16_bf16,
//                K-half phases, reads-before-barrier (R11) + WIDENED XOR
//                SWIZZLE s(row,c) = c ^ (row&7) ^ ((row>>3&3)<<1):
//                R11's swizzle (c ^ row&7) left only lane-bit-5 varying the
//                chunk phase in strided lane groups -> 4-way bank conflict
//                (7.55e7, same as R3 -- the 32x32 confound both times).
//                The (row>>3&3)<<1 term folds lane bits 3-4 in -> all 8
//                chunks distinct in both strided and consecutive groups.

typedef unsigned short u16;
typedef __attribute__((ext_vector_type(4)))  float  f32x4;
typedef __attribute__((ext_vector_type(16))) float  f32x16;
typedef __attribute__((ext_vector_type(8)))  __bf16 bf16x8;
typedef __attribute__((ext_vector_type(8)))  short  s16x8;

#define MDIM 8192
#define NDIM 4096
#define KDIM 4096

__device__ __forceinline__ u16 f2bf(float f) {
    union { float f; unsigned int u; } v;
    v.f = f;
    unsigned int r = v.u + 0x7FFFu + ((v.u >> 16) & 1u);  // RNE
    return (u16)(r >> 16);
}

// ---------------- Kernel 1: X fp32 -> bf16 ----------------
__global__ void __launch_bounds__(256) cvt_x_kernel(const float* __restrict__ X,
                                                    u16* __restrict__ Xb, int nvec8) {
    int stride = gridDim.x * blockDim.x;
    for (int i = blockIdx.x * blockDim.x + threadIdx.x; i < nvec8; i += stride) {
        f32x4 x0 = ((const f32x4*)X)[2 * i];
        f32x4 x1 = ((const f32x4*)X)[2 * i + 1];
        s16x8 o;
        o[0] = (short)f2bf(x0[0]); o[1] = (short)f2bf(x0[1]);
        o[2] = (short)f2bf(x0[2]); o[3] = (short)f2bf(x0[3]);
        o[4] = (short)f2bf(x1[0]); o[5] = (short)f2bf(x1[1]);
        o[6] = (short)f2bf(x1[2]); o[7] = (short)f2bf(x1[3]);
        ((s16x8*)Xb)[i] = o;
    }
}

// ---------------- Kernel 2: W' = bf16(W + 2*B@A), z = projection ----------------
__global__ void __launch_bounds__(256) merge_w3_kernel(const float* __restrict__ QW,
                                                       const float* __restrict__ QA,
                                                       const float* __restrict__ QB,
                                                       const float* __restrict__ KW,
                                                       const float* __restrict__ KA,
                                                       const float* __restrict__ KB,
                                                       const float* __restrict__ VW,
                                                       const float* __restrict__ VA,
                                                       const float* __restrict__ VB,
                                                       u16* __restrict__ WbAll) {
    const int z = blockIdx.z;
    const float* W  = (z == 0) ? QW : (z == 1) ? KW : VW;
    const float* A  = (z == 0) ? QA : (z == 1) ? KA : VA;
    const float* Bm = (z == 0) ? QB : (z == 1) ? KB : VB;
    u16* Wb = WbAll + (size_t)z * NDIM * KDIM;

    __shared__ float As[16][64];
    const int t  = threadIdx.x;
    const int hb = blockIdx.x * 64;
    const int nb = blockIdx.y * 128;

    {   // stage A[16][hb:hb+64]
        int r = t >> 4, c = (t & 15) * 4;
        *(f32x4*)&As[r][c] = *(const f32x4*)&A[r * 4096 + hb + c];
    }
    __syncthreads();

    const int hl = (t & 7) * 8;
    const int n0 = nb + (t >> 3) * 4;

    float bv[4][16];
    float s[4][8];
#pragma unroll
    for (int i = 0; i < 4; i++) {
        const float* br = &Bm[(size_t)(n0 + i) * 16];
#pragma unroll
        for (int r = 0; r < 16; r++) bv[i][r] = 2.0f * br[r];
        f32x4 w0 = *(const f32x4*)&W[(size_t)(n0 + i) * 4096 + hb + hl];
        f32x4 w1 = *(const f32x4*)&W[(size_t)(n0 + i) * 4096 + hb + hl + 4];
        s[i][0] = w0[0]; s[i][1] = w0[1]; s[i][2] = w0[2]; s[i][3] = w0[3];
        s[i][4] = w1[0]; s[i][5] = w1[1]; s[i][6] = w1[2]; s[i][7] = w1[3];
    }
#pragma unroll
    for (int r = 0; r < 16; r++) {
        f32x4 a0 = *(const f32x4*)&As[r][hl];
        f32x4 a1 = *(const f32x4*)&As[r][hl + 4];
#pragma unroll
        for (int i = 0; i < 4; i++) {
            s[i][0] += bv[i][r] * a0[0]; s[i][1] += bv[i][r] * a0[1];
            s[i][2] += bv[i][r] * a0[2]; s[i][3] += bv[i][r] * a0[3];
            s[i][4] += bv[i][r] * a1[0]; s[i][5] += bv[i][r] * a1[1];
            s[i][6] += bv[i][r] * a1[2]; s[i][7] += bv[i][r] * a1[3];
        }
    }
#pragma unroll
    for (int i = 0; i < 4; i++) {
        s16x8 o;
#pragma unroll
        for (int j = 0; j < 8; j++) o[j] = (short)f2bf(s[i][j]);
        *(s16x8*)&Wb[(size_t)(n0 + i) * 4096 + hb + hl] = o;
    }
}

// ---------------- Kernel 3: 256x256 GEMM, 32x32x16, K-half phases ----------------
// 8 waves (2M x 4N), per-wave 128x64 out: acc[4][2] f32x16 (128 AGPRs).
// LDS 128 KiB: A[2][256][64] + B[2][256][64] bf16.
// Swizzle (16B chunks): s(row,c) = c ^ (row&7) ^ (((row>>3)&3)<<1)
//   - stage (linear LDS dst): source col = s(row, lane&7); row = blk*8+lane>>3
//     -> (lane&7) ^ (lane>>3) ^ ((blk&3)<<1)   [h*16 and blk*8 don't disturb
//     row&7 = lane>>3 and (row>>3)&3 = blk&3]
//   - read: chunk = (2ks+hi) ^ (l31&7) ^ ((l31>>3)<<1)   [(row>>3)&3 = l31>>3
//     for both A (mi*32 rows) and B (ni*32, wn*64 rows): all multiples of 4]
// Bank check: strided lane group {x+8g}: chunks (2ks+hi)^x^(g<<1) -> parity
// flips with hi, evens span with g -> 8 distinct. Consecutive octet: varies
// with lane&7 -> 8 distinct.
//
// Phases per K-tile T (kh = K-half), 12 live operand regs:
//   alpha: rd kh0 (12); STG A(T+1)+B(T+1); BAR; 16 MFMA; BAR
//   beta:  rd kh1 (12); BAR; 16 MFMA; vmcnt(0); BAR
// WAR: STG(alpha,T) targets parity bufs last read in beta(T-1) pre-BAR ->
// >=1 barrier earlier. vmcnt(0) at beta end: stages issued ~1.5 phases
// earlier (> HBM latency); BAR publishes before alpha(T+1) reads.

#define BM 256
#define BN 256
#define BK 64

#define BAR() asm volatile("s_barrier" ::: "memory")
#define WAIT_VM(n) asm volatile("s_waitcnt vmcnt(" #n ")" ::: "memory")
#define PRIO(p) __builtin_amdgcn_s_setprio(p)

__global__ void __launch_bounds__(512, 2) gemm8_kernel(const u16* __restrict__ Xb,
                                                       const u16* __restrict__ Wb,
                                                       float* __restrict__ out) {
    extern __shared__ char lds[];

    const int t    = threadIdx.x;
    const int lane = t & 63;
    const int w    = t >> 6;      // wave 0..7
    const int wr   = w >> 2;      // M wave 0..1
    const int wn   = w & 3;       // N wave 0..3
    const int l31  = lane & 31;
    const int hi   = lane >> 5;   // k-half within fragment
    const int swz2 = (l31 & 7) ^ ((l31 >> 3) << 1);   // widened read swizzle

    // Z-sequential XCD-bijective remap (R8): z = orig/512 sequential bands;
    // within z: i = (r&7)*64 + r/8 (bijective, 512 = 8 x 64).
    const int orig = blockIdx.x;
    const int z    = orig >> 9;
    const int r0   = orig & 511;
    const int i_   = (r0 & 7) * 64 + (r0 >> 3);
    const int nT = i_ & 15;
    const int mT = i_ >> 4;
    const int mBase = mT * BM;
    const int nBase = nT * BN;

    const u16* Wp = Wb + (size_t)z * NDIM * KDIM;
    const char* gA = (const char*)Xb + (size_t)mBase * (KDIM * 2);
    const char* gB = (const char*)Wp + (size_t)nBase * (KDIM * 2);

    char* ldsA0 = lds;
    char* ldsA1 = lds + 32768;
    char* ldsB0 = lds + 65536;
    char* ldsB1 = lds + 98304;

    // staging: 2 x global_load_lds(16B)/wave/half-tile, linear LDS dst,
    // pre-swizzled global source column (self-inverse XOR, rule 21):
    //   blk0 = w*2 (j=0), blk1 = w*2+1 (j=1); extra term ((blk&3)<<1)
    const int blkrow = lane >> 3;
    const int blk0 = (w << 1) | 0, blk1 = (w << 1) | 1;
    const int colswz0 = (((lane & 7) ^ blkrow ^ ((blk0 & 3) << 1)) << 4);
    const int colswz1 = (((lane & 7) ^ blkrow ^ ((blk1 & 3) << 1)) << 4);
    const size_t stg0 = (size_t)(blk0 * 8 + blkrow) * (KDIM * 2) + colswz0;
    const size_t stg1 = (size_t)(blk1 * 8 + blkrow) * (KDIM * 2) + colswz1;
    const int ldsStg0 = (blk0 << 10) + lane * 16;
    const int ldsStg1 = (blk1 << 10) + lane * 16;

#define STAGE(ldsTile, gtile, h, kt)                                              \
  { __builtin_amdgcn_global_load_lds(                                             \
        (const __attribute__((address_space(1))) void*)((gtile) + stg0 +          \
            (size_t)(h) * (128 * KDIM * 2) + (size_t)(kt) * 128),                 \
        (__attribute__((address_space(3))) void*)((ldsTile) + (h) * 16384 + ldsStg0), \
        16, 0, 0);                                                                \
    __builtin_amdgcn_global_load_lds(                                             \
        (const __attribute__((address_space(1))) void*)((gtile) + stg1 +          \
            (size_t)(h) * (128 * KDIM * 2) + (size_t)(kt) * 128),                 \
        (__attribute__((address_space(3))) void*)((ldsTile) + (h) * 16384 + ldsStg1), \
        16, 0, 0); }

#define STG4(pA, pB, kt)                                                          \
  { STAGE(pA, gA, 0, kt) STAGE(pA, gA, 1, kt)                                     \
    STAGE(pB, gB, 0, kt) STAGE(pB, gB, 1, kt) }

    // ds_read (32x32x16 fragment, R3/R11-verified addressing + new swizzle):
    // row = panel + mi*32 + l31; chunk = (2ks+hi) ^ swz2
    const int rA0 = (wr * 128 + l31) * 128;
    const int rB0 = (wn * 64 + l31) * 128;
#define RD_A(tile, mi, ks) (*(const bf16x8*)((tile) + rA0 + (mi) * 4096 + (((((ks) << 1) | hi) ^ swz2) << 4)))
#define RD_B(tile, ni, ks) (*(const bf16x8*)((tile) + rB0 + (ni) * 4096 + (((((ks) << 1) | hi) ^ swz2) << 4)))

    f32x16 acc[4][2] = {};
    bf16x8 a[4][2], b[2][2];

// reads for one K-half (12 x ds_read_b128), consumption order
#define RDS(pA, pB, kh)                                                           \
    a[0][0] = RD_A(pA, 0, 2*(kh));   a[0][1] = RD_A(pA, 0, 2*(kh)+1);             \
    b[0][0] = RD_B(pB, 0, 2*(kh));   b[0][1] = RD_B(pB, 0, 2*(kh)+1);             \
    a[1][0] = RD_A(pA, 1, 2*(kh));   a[1][1] = RD_A(pA, 1, 2*(kh)+1);             \
    b[1][0] = RD_B(pB, 1, 2*(kh));   b[1][1] = RD_B(pB, 1, 2*(kh)+1);             \
    a[2][0] = RD_A(pA, 2, 2*(kh));   a[2][1] = RD_A(pA, 2, 2*(kh)+1);             \
    a[3][0] = RD_A(pA, 3, 2*(kh));   a[3][1] = RD_A(pA, 3, 2*(kh)+1);

// 16 MFMA
#define MFMAS()                                                                   \
    PRIO(1);                                                                      \
    _Pragma("unroll") for (int ks = 0; ks < 2; ++ks)                              \
    _Pragma("unroll") for (int mi = 0; mi < 4; ++mi)                              \
    _Pragma("unroll") for (int ni = 0; ni < 2; ++ni)                              \
      acc[mi][ni] = __builtin_amdgcn_mfma_f32_32x32x16_bf16(                      \
          a[mi][ks], b[ni][ks], acc[mi][ni], 0, 0, 0);                            \
    PRIO(0);

// alpha: reads kh0; stage T+1 (A+B); BAR; MFMA; BAR
#define PHA(pA, pB, STG)                                                          \
  { RDS(pA, pB, 0) STG; BAR(); MFMAS() BAR(); }

// beta: reads kh1; BAR; MFMA; vmcnt; BAR
#define PHB(pA, pB, VMW)                                                          \
  { RDS(pA, pB, 1) BAR(); MFMAS() VMW; BAR(); }

    // ---- prologue: stage tile 0 (A+B), drain, publish ----
    STAGE(ldsA0, gA, 0, 0) STAGE(ldsA0, gA, 1, 0)
    STAGE(ldsB0, gB, 0, 0) STAGE(ldsB0, gB, 1, 0)
    WAIT_VM(0);
    BAR();

    // ---- main loop: 31 iterations (tiles T=2i, T+1), T = 0..60 ----
    for (int i = 0; i < 31; ++i) {
        const int T = 2 * i;
        PHA(ldsA0, ldsB0, STG4(ldsA1, ldsB1, T + 1));
        PHB(ldsA0, ldsB0, WAIT_VM(0));
        PHA(ldsA1, ldsB1, STG4(ldsA0, ldsB0, T + 2));
        PHB(ldsA1, ldsB1, WAIT_VM(0));
    }

    // ---- peeled last pair (tiles 62, 63) ----
    PHA(ldsA0, ldsB0, STG4(ldsA1, ldsB1, 63));
    PHB(ldsA0, ldsB0, WAIT_VM(0));
    PHA(ldsA1, ldsB1, );
    PHB(ldsA1, ldsB1, );

    // ---- epilogue: 32x32 C/D layout (m74/m101, R3-verified):
    //      col = lane&31, row = (reg&3) + 8*(reg>>2) + 4*hi ----
    float* C = out + (size_t)z * MDIM * NDIM;
#pragma unroll
    for (int mi = 0; mi < 4; ++mi) {
#pragma unroll
        for (int ni = 0; ni < 2; ++ni) {
            const int col  = nBase + wn * 64 + ni * 32 + l31;
            const int rowb = mBase + wr * 128 + mi * 32 + 4 * hi;
            f32x16 v = acc[mi][ni];
#pragma unroll
            for (int reg = 0; reg < 16; ++reg) {
                const int row = rowb + (reg & 3) + 8 * (reg >> 2);
                C[(size_t)row * NDIM + col] = v[reg];
            }
        }
    }
}

// ---------------- host launch ----------------
extern "C" void kernel_launch(void* const* d_in, const int* in_sizes, int n_in,
                              void* d_out, int out_size, void* d_ws, size_t ws_size,
                              hipStream_t stream) {
    const float* X  = (const float*)d_in[0];
    const float* QW = (const float*)d_in[1];
    const float* QA = (const float*)d_in[2];
    const float* QB = (const float*)d_in[3];
    const float* KW = (const float*)d_in[4];
    const float* KA = (const float*)d_in[5];
    const float* KB = (const float*)d_in[6];
    const float* VW = (const float*)d_in[7];
    const float* VA = (const float*)d_in[8];
    const float* VB = (const float*)d_in[9];
    float* out = (float*)d_out;

    u16* Xb = (u16*)d_ws;                                        // 64 MiB
    u16* Wb = (u16*)((char*)d_ws + (size_t)MDIM * KDIM * 2);     // 3 x 32 MiB

    (void)hipFuncSetAttribute((const void*)gemm8_kernel,
                              hipFuncAttributeMaxDynamicSharedMemorySize, 131072);

    cvt_x_kernel<<<2048, 256, 0, stream>>>(X, Xb, (MDIM * KDIM) / 8);

    dim3 wgrid(4096 / 64, 4096 / 128, 3);
    merge_w3_kernel<<<wgrid, 256, 0, stream>>>(QW, QA, QB, KW, KA, KB, VW, VA, VB, Wb);

    gemm8_kernel<<<dim3(16 * 32 * 3), dim3(512), 131072, stream>>>(Xb, Wb, out);
}

// Round 13
// 742.992 us; speedup vs baseline: 1.2572x; 1.2572x over previous
//
#include <hip/hip_runtime.h>

// FusedLoRAQKV on MI355X (gfx950).
// Y_p = X @ (W_p + 2 * B_p @ A_p)^T  for p in {Q,K,V}
//
// Pipeline:
//   1. cvt_x:    X fp32 -> bf16
//   2. merge_w3: W' = bf16(W + 2*B@A), all three projections, one launch
//   3. gemm:     256x256 tile, BK=64, 8 waves, mfma_f32_16x16x32_bf16
//                (32x32 dropped: fixed +4cyc/read LDS penalty, swizzle-
//                invariant across R3/R11/R12), XOR-swizzled LDS (0 conflicts),
//                single-barrier phases {BAR; reads; stage; MFMA}, 12/8/4/0
//                reads, vmcnt(4)@P4/vmcnt(6)@P8, z-sequential XCD remap,
//                + LDS-TRANSPOSED EPILOGUE: acc -> LDS (C-layout) -> 1KB-
//                contiguous full-line nontemporal dwordx4 stores. Replaces
//                128 scalar 64B-segment stores/wave that were flushing X/B
//                out of L3 (FETCH 950MB vs 160MB resident).

typedef unsigned short u16;
typedef __attribute__((ext_vector_type(4))) float  f32x4;
typedef __attribute__((ext_vector_type(8))) __bf16 bf16x8;
typedef __attribute__((ext_vector_type(8))) short  s16x8;

#define MDIM 8192
#define NDIM 4096
#define KDIM 4096

__device__ __forceinline__ u16 f2bf(float f) {
    union { float f; unsigned int u; } v;
    v.f = f;
    unsigned int r = v.u + 0x7FFFu + ((v.u >> 16) & 1u);  // RNE
    return (u16)(r >> 16);
}

// ---------------- Kernel 1: X fp32 -> bf16 ----------------
__global__ void __launch_bounds__(256) cvt_x_kernel(const float* __restrict__ X,
                                                    u16* __restrict__ Xb, int nvec8) {
    int stride = gridDim.x * blockDim.x;
    for (int i = blockIdx.x * blockDim.x + threadIdx.x; i < nvec8; i += stride) {
        f32x4 x0 = ((const f32x4*)X)[2 * i];
        f32x4 x1 = ((const f32x4*)X)[2 * i + 1];
        s16x8 o;
        o[0] = (short)f2bf(x0[0]); o[1] = (short)f2bf(x0[1]);
        o[2] = (short)f2bf(x0[2]); o[3] = (short)f2bf(x0[3]);
        o[4] = (short)f2bf(x1[0]); o[5] = (short)f2bf(x1[1]);
        o[6] = (short)f2bf(x1[2]); o[7] = (short)f2bf(x1[3]);
        ((s16x8*)Xb)[i] = o;
    }
}

// ---------------- Kernel 2: W' = bf16(W + 2*B@A), z = projection ----------------
__global__ void __launch_bounds__(256) merge_w3_kernel(const float* __restrict__ QW,
                                                       const float* __restrict__ QA,
                                                       const float* __restrict__ QB,
                                                       const float* __restrict__ KW,
                                                       const float* __restrict__ KA,
                                                       const float* __restrict__ KB,
                                                       const float* __restrict__ VW,
                                                       const float* __restrict__ VA,
                                                       const float* __restrict__ VB,
                                                       u16* __restrict__ WbAll) {
    const int z = blockIdx.z;
    const float* W  = (z == 0) ? QW : (z == 1) ? KW : VW;
    const float* A  = (z == 0) ? QA : (z == 1) ? KA : VA;
    const float* Bm = (z == 0) ? QB : (z == 1) ? KB : VB;
    u16* Wb = WbAll + (size_t)z * NDIM * KDIM;

    __shared__ float As[16][64];
    const int t  = threadIdx.x;
    const int hb = blockIdx.x * 64;
    const int nb = blockIdx.y * 128;

    {   // stage A[16][hb:hb+64]
        int r = t >> 4, c = (t & 15) * 4;
        *(f32x4*)&As[r][c] = *(const f32x4*)&A[r * 4096 + hb + c];
    }
    __syncthreads();

    const int hl = (t & 7) * 8;
    const int n0 = nb + (t >> 3) * 4;

    float bv[4][16];
    float s[4][8];
#pragma unroll
    for (int i = 0; i < 4; i++) {
        const float* br = &Bm[(size_t)(n0 + i) * 16];
#pragma unroll
        for (int r = 0; r < 16; r++) bv[i][r] = 2.0f * br[r];
        f32x4 w0 = *(const f32x4*)&W[(size_t)(n0 + i) * 4096 + hb + hl];
        f32x4 w1 = *(const f32x4*)&W[(size_t)(n0 + i) * 4096 + hb + hl + 4];
        s[i][0] = w0[0]; s[i][1] = w0[1]; s[i][2] = w0[2]; s[i][3] = w0[3];
        s[i][4] = w1[0]; s[i][5] = w1[1]; s[i][6] = w1[2]; s[i][7] = w1[3];
    }
#pragma unroll
    for (int r = 0; r < 16; r++) {
        f32x4 a0 = *(const f32x4*)&As[r][hl];
        f32x4 a1 = *(const f32x4*)&As[r][hl + 4];
#pragma unroll
        for (int i = 0; i < 4; i++) {
            s[i][0] += bv[i][r] * a0[0]; s[i][1] += bv[i][r] * a0[1];
            s[i][2] += bv[i][r] * a0[2]; s[i][3] += bv[i][r] * a0[3];
            s[i][4] += bv[i][r] * a1[0]; s[i][5] += bv[i][r] * a1[1];
            s[i][6] += bv[i][r] * a1[2]; s[i][7] += bv[i][r] * a1[3];
        }
    }
#pragma unroll
    for (int i = 0; i < 4; i++) {
        s16x8 o;
#pragma unroll
        for (int j = 0; j < 8; j++) o[j] = (short)f2bf(s[i][j]);
        *(s16x8*)&Wb[(size_t)(n0 + i) * 4096 + hb + hl] = o;
    }
}

// ---------------- Kernel 3: 256x256 single-barrier-phase GEMM ----------------
// 8 waves (2M x 4N), per-wave 128x64 out, acc[8][4] f32x4 (16x16x32 MFMA).
// LDS 128 KiB: A[2][256][64] + B[2][256][64] bf16, 16B-chunk XOR swizzle
// (chunk ^= row&7), linear-dst global_load_lds + pre-swizzled source.
//
// Phase = { BAR ; ds_reads ; stage ; [vmcnt] ; MFMA }.  ONE barrier/phase.
//   P1: rd 12 (aR1, bR01); STG; Q1 = aR1 x bR01
//   P2: rd 8  (b23, aR2a); STG; Q2 = aR1 x bR23
//   P3: rd 4  (aR2b);      STG; Q3 = aR2 x bR01
//   P4:                    STG; vmcnt; Q4 = aR2 x bR23
// WAR/vmcnt audits as R7/R8 (verified): A-buf staged P5/P6 (last read P3);
// B-buf staged P3/P4 (last read P2); carry into P1 = 6; P4: vmcnt(4);
// P8: vmcnt(6).
//
// Epilogue: one BAR (all waves' K-loop LDS reads complete before it ->
// LDS reusable), then 2 rounds of {wr==round waves dump acc to LDS f32
// [128][256]; BAR; all 8 waves store 16 rows each as 64-lane f32x4 = 1KB
// contiguous full-line nontemporal stores; BAR}.

#define BM 256
#define BN 256
#define BK 64

#define BAR() asm volatile("s_barrier" ::: "memory")
#define WAIT_VM(n) asm volatile("s_waitcnt vmcnt(" #n ")" ::: "memory")
#define PRIO(p) __builtin_amdgcn_s_setprio(p)

__global__ void __launch_bounds__(512, 2) gemm8_kernel(const u16* __restrict__ Xb,
                                                       const u16* __restrict__ Wb,
                                                       float* __restrict__ out) {
    extern __shared__ char lds[];

    const int t    = threadIdx.x;
    const int lane = t & 63;
    const int w    = t >> 6;      // wave 0..7
    const int wr   = w >> 2;      // M wave 0..1
    const int wn   = w & 3;       // N wave 0..3
    const int lr   = lane & 15;
    const int lkq  = lane >> 4;
    const int lr7  = lr & 7;

    // Z-sequential XCD-bijective remap (R8): z = orig/512 sequential bands;
    // within z: i = (r&7)*64 + r/8 (bijective, 512 = 8 x 64).
    const int orig = blockIdx.x;
    const int z    = orig >> 9;
    const int r0   = orig & 511;
    const int i_   = (r0 & 7) * 64 + (r0 >> 3);
    const int nT = i_ & 15;
    const int mT = i_ >> 4;
    const int mBase = mT * BM;
    const int nBase = nT * BN;

    const u16* Wp = Wb + (size_t)z * NDIM * KDIM;
    const char* gA = (const char*)Xb + (size_t)mBase * (KDIM * 2);
    const char* gB = (const char*)Wp + (size_t)nBase * (KDIM * 2);

    char* ldsA0 = lds;
    char* ldsA1 = lds + 32768;
    char* ldsB0 = lds + 65536;
    char* ldsB1 = lds + 98304;

    // staging: 2 x global_load_lds(16B)/wave/half-tile, linear LDS dst,
    // pre-swizzled global source column (involution, rule 21)
    const int blkrow = lane >> 3;
    const int colswz = ((lane & 7) ^ blkrow) << 4;
    const size_t stg0 = (size_t)(((w << 1) | 0) * 8 + blkrow) * (KDIM * 2) + colswz;
    const size_t stg1 = (size_t)(((w << 1) | 1) * 8 + blkrow) * (KDIM * 2) + colswz;
    const int ldsStg0 = (((w << 1) | 0) << 10) + lane * 16;
    const int ldsStg1 = (((w << 1) | 1) << 10) + lane * 16;

#define STAGE(ldsTile, gtile, h, kt)                                              \
  { __builtin_amdgcn_global_load_lds(                                             \
        (const __attribute__((address_space(1))) void*)((gtile) + stg0 +          \
            (size_t)(h) * (128 * KDIM * 2) + (size_t)(kt) * 128),                 \
        (__attribute__((address_space(3))) void*)((ldsTile) + (h) * 16384 + ldsStg0), \
        16, 0, 0);                                                                \
    __builtin_amdgcn_global_load_lds(                                             \
        (const __attribute__((address_space(1))) void*)((gtile) + stg1 +          \
            (size_t)(h) * (128 * KDIM * 2) + (size_t)(kt) * 128),                 \
        (__attribute__((address_space(3))) void*)((ldsTile) + (h) * 16384 + ldsStg1), \
        16, 0, 0); }

    // ds_read: row*128 + (((kk<<2)|lkq) ^ (row&7))*16 ; row&7 == lr7
    const int csA = (lkq << 4) ^ (lr7 << 4);
    const int rA0 = (wr * 128 + lr) * 128;
    const int rB0 = (wn * 64 + lr) * 128;
#define RD_A(tile, mi, kk) (*(const bf16x8*)((tile) + rA0 + (mi) * 2048 + (((kk) << 6) ^ csA)))
#define RD_B(tile, ni, kk) (*(const bf16x8*)((tile) + rB0 + (ni) * 2048 + (((kk) << 6) ^ csA)))

    f32x4 acc[8][4] = {};
    bf16x8 aR1[4][2], aR2[4][2], bR[4][2];

#define MFMA_Q(AF, mbase, nbase)                                                   \
    PRIO(1);                                                                       \
    _Pragma("unroll") for (int mi = 0; mi < 4; ++mi)                               \
    _Pragma("unroll") for (int ni = 0; ni < 2; ++ni)                               \
    _Pragma("unroll") for (int kk = 0; kk < 2; ++kk)                               \
      acc[(mbase) + mi][(nbase) + ni] = __builtin_amdgcn_mfma_f32_16x16x32_bf16(   \
          AF[mi][kk], bR[(nbase) + ni][kk], acc[(mbase) + mi][(nbase) + ni], 0, 0, 0); \
    PRIO(0);

// P1: BAR; 12 reads (consumption order); stage; Q1 = aR1 x bR[0,1]
#define PH1(pA, pB, STG)                                                           \
  { BAR();                                                                         \
    aR1[0][0] = RD_A(pA, 0, 0); aR1[0][1] = RD_A(pA, 0, 1);                        \
    bR[0][0]  = RD_B(pB, 0, 0); bR[0][1]  = RD_B(pB, 0, 1);                        \
    aR1[1][0] = RD_A(pA, 1, 0); aR1[1][1] = RD_A(pA, 1, 1);                        \
    bR[1][0]  = RD_B(pB, 1, 0); bR[1][1]  = RD_B(pB, 1, 1);                        \
    aR1[2][0] = RD_A(pA, 2, 0); aR1[2][1] = RD_A(pA, 2, 1);                        \
    aR1[3][0] = RD_A(pA, 3, 0); aR1[3][1] = RD_A(pA, 3, 1);                        \
    STG; MFMA_Q(aR1, 0, 0) }

// P2: BAR; 8 reads (b23 first -- consumed by this phase's Q2); Q2 = aR1 x bR[2,3]
#define PH2(pA, pB, STG)                                                           \
  { BAR();                                                                         \
    bR[2][0] = RD_B(pB, 2, 0); bR[2][1] = RD_B(pB, 2, 1);                          \
    bR[3][0] = RD_B(pB, 3, 0); bR[3][1] = RD_B(pB, 3, 1);                          \
    aR2[0][0] = RD_A(pA, 4, 0); aR2[0][1] = RD_A(pA, 4, 1);                        \
    aR2[1][0] = RD_A(pA, 5, 0); aR2[1][1] = RD_A(pA, 5, 1);                        \
    STG; MFMA_Q(aR1, 0, 2) }

// P3: BAR; 4 reads; Q3 = aR2 x bR[0,1]
#define PH3(pA, STG)                                                               \
  { BAR();                                                                         \
    aR2[2][0] = RD_A(pA, 6, 0); aR2[2][1] = RD_A(pA, 6, 1);                        \
    aR2[3][0] = RD_A(pA, 7, 0); aR2[3][1] = RD_A(pA, 7, 1);                        \
    STG; MFMA_Q(aR2, 4, 0) }

// P4: BAR; stage; counted vmcnt; Q4 = aR2 x bR[2,3]
#define PH4(STG, VMW)                                                              \
  { BAR(); STG; VMW; MFMA_Q(aR2, 4, 2) }

#define PH4F()                                                                     \
  { BAR(); MFMA_Q(aR2, 4, 2) }

    // ---- prologue: A(0) full, B(0) full, B(1) full, A(1).Ah0 = 14 loads ----
    STAGE(ldsA0, gA, 0, 0); STAGE(ldsA0, gA, 1, 0);
    STAGE(ldsB0, gB, 0, 0); STAGE(ldsB0, gB, 1, 0);
    STAGE(ldsB1, gB, 0, 1); STAGE(ldsB1, gB, 1, 1);
    STAGE(ldsA1, gA, 0, 1);
    WAIT_VM(6);   // drain A(0)+B(0); leftover 6 = B(1)+A(1).Ah0 = steady carry

    // ---- main loop: 31 iterations (tiles T=2i, T+1), T = 0..60 ----
    for (int i = 0; i < 31; ++i) {
        const int T = 2 * i;
        PH1(ldsA0, ldsB0, STAGE(ldsA1, gA, 1, T + 1));                   // A(T+1).Ah1
        PH2(ldsA0, ldsB0, );                                             // no stage
        PH3(ldsA0,        STAGE(ldsB0, gB, 0, T + 2));                   // B(T+2).Bh0
        PH4(              STAGE(ldsB0, gB, 1, T + 2), WAIT_VM(4));       // B(T+2).Bh1
        PH1(ldsA1, ldsB1, STAGE(ldsA0, gA, 0, T + 2));                   // A(T+2).Ah0
        PH2(ldsA1, ldsB1, STAGE(ldsA0, gA, 1, T + 2));                   // A(T+2).Ah1
        PH3(ldsA1,        STAGE(ldsB1, gB, 0, T + 3));                   // B(T+3).Bh0
        PH4(              { STAGE(ldsB1, gB, 1, T + 3)                   // B(T+3).Bh1
                            STAGE(ldsA1, gA, 0, T + 3) }, WAIT_VM(6));   // A(T+3).Ah0
    }

    // ---- peeled last pair (tiles 62, 63) ----
    PH1(ldsA0, ldsB0, STAGE(ldsA1, gA, 1, 63));                          // A(63).Ah1
    PH2(ldsA0, ldsB0, );
    PH3(ldsA0, );
    PH4(, WAIT_VM(0));                                                   // all landed
    PH1(ldsA1, ldsB1, );
    PH2(ldsA1, ldsB1, );
    PH3(ldsA1, );
    PH4F();

    // ---- epilogue: LDS-transpose + full-line nontemporal stores ----
    // BAR: every wave's LDS reads were consumed (lgkm-waited) before its
    // MFMAs above; all waves arriving => all K-loop LDS reads complete.
    BAR();
    float* C    = out + (size_t)z * MDIM * NDIM;
    float* ldsf = (float*)lds;                    // f32 [128][256] = 128 KiB
#pragma unroll
    for (int round = 0; round < 2; ++round) {
        if (wr == round) {
            // dump acc into LDS in C layout (rows relative to wr*128)
#pragma unroll
            for (int mi = 0; mi < 8; ++mi) {
#pragma unroll
                for (int ni = 0; ni < 4; ++ni) {
                    const int lrow = mi * 16 + lkq * 4;
                    const int col  = wn * 64 + ni * 16 + lr;
                    f32x4 v = acc[mi][ni];
#pragma unroll
                    for (int j = 0; j < 4; ++j)
                        ldsf[(lrow + j) * 256 + col] = v[j];
                }
            }
        }
        BAR();
        // all 8 waves: store 16 rows each; 64 lanes x f32x4 = 1KB/row segment
        const size_t gb = (size_t)(mBase + round * 128) * NDIM + nBase;
#pragma unroll
        for (int rr = 0; rr < 16; ++rr) {
            const int row = w * 16 + rr;
            f32x4 v = *(const f32x4*)&ldsf[row * 256 + lane * 4];
            __builtin_nontemporal_store(v,
                (f32x4*)(C + gb + (size_t)row * NDIM + lane * 4));
        }
        BAR();   // before next round overwrites LDS
    }
}

// ---------------- host launch ----------------
extern "C" void kernel_launch(void* const* d_in, const int* in_sizes, int n_in,
                              void* d_out, int out_size, void* d_ws, size_t ws_size,
                              hipStream_t stream) {
    const float* X  = (const float*)d_in[0];
    const float* QW = (const float*)d_in[1];
    const float* QA = (const float*)d_in[2];
    const float* QB = (const float*)d_in[3];
    const float* KW = (const float*)d_in[4];
    const float* KA = (const float*)d_in[5];
    const float* KB = (const float*)d_in[6];
    const float* VW = (const float*)d_in[7];
    const float* VA = (const float*)d_in[8];
    const float* VB = (const float*)d_in[9];
    float* out = (float*)d_out;

    u16* Xb = (u16*)d_ws;                                        // 64 MiB
    u16* Wb = (u16*)((char*)d_ws + (size_t)MDIM * KDIM * 2);     // 3 x 32 MiB

    (void)hipFuncSetAttribute((const void*)gemm8_kernel,
                              hipFuncAttributeMaxDynamicSharedMemorySize, 131072);

    cvt_x_kernel<<<2048, 256, 0, stream>>>(X, Xb, (MDIM * KDIM) / 8);

    dim3 wgrid(4096 / 64, 4096 / 128, 3);
    merge_w3_kernel<<<wgrid, 256, 0, stream>>>(QW, QA, QB, KW, KA, KB, VW, VA, VB, Wb);

    gemm8_kernel<<<dim3(16 * 32 * 3), dim3(512), 131072, stream>>>(Xb, Wb, out);
}